// Round 4
// baseline (307.665 us; speedup 1.0000x reference)
//
#include <hip/hip_runtime.h>
#include <hip/hip_bf16.h>

typedef __attribute__((ext_vector_type(4))) float  f32x4;
typedef __attribute__((ext_vector_type(2))) float  f32x2;
typedef __attribute__((ext_vector_type(8))) short  s16x8;
typedef __attribute__((ext_vector_type(4))) short  s16x4;

#define NB_    16
#define NH_    128
#define NS_    4096
#define ND_    512
#define NDPE_  64
#define NDT_   576           // 512 + 64
#define NCHUNK 16
#define CHUNK_ 256
#define TS_    32
#define NSUB_  8
#define NT_    512

#define KROW_S 584   // kbuf row: 576 + 8 pad shorts (292 dwords == 4 mod 32)
#define VT_ROW 34    // vbufT row: 32 + 2 pad shorts (17 dwords, odd)
#define PROW   40    // pbuf row

#define RAW_BYTES  (TS_ * NDT_ * 4)          // 73728 raw f32 staging
#define KBUF_OFF   RAW_BYTES
#define KBUF_BYTES (TS_ * KROW_S * 2)        // 37376
#define VBUF_OFF   (KBUF_OFF + KBUF_BYTES)   // 111104
#define VBUF_BYTES (ND_ * VT_ROW * 2)        // 34816
#define PBUF_OFF   (VBUF_OFF + VBUF_BYTES)   // 145920
#define SMEM_BYTES (PBUF_OFF + 8 * 16 * PROW * 2)  // 156160 <= 163840

// (1/sqrt(576)) * log2(e)
#define CL2  0.06011229337037348f
#define TDEF 2.0f   // defer-max threshold (base-2 units): P bounded by 4

__device__ __forceinline__ unsigned pk_bf16(float a, float b) {
    union { __hip_bfloat162 h2; unsigned u; } c;
    c.h2 = __float22bfloat162_rn(make_float2(a, b));
    return c.u;
}
__device__ __forceinline__ unsigned short bf1(float a) {
    union { __hip_bfloat16 h; unsigned short u; } c;
    c.h = __float2bfloat16(a);
    return c.u;
}

// global f32 -> LDS, 16 B per lane, dest = wave-uniform base + lane*16
__device__ __forceinline__ void gl_lds16(const float* src, char* lds) {
    __builtin_amdgcn_global_load_lds(
        (const __attribute__((address_space(1))) void*)src,
        (__attribute__((address_space(3))) void*)lds,
        16, 0, 0);
}

// issue the 9 DMA loads for this wave covering rawbuf = [32][576] f32 row-major
__device__ __forceinline__ void dma_tile(char* smem, const float* kT, const float* peT,
                                         int wv, int l) {
    #pragma unroll
    for (int i = 0; i < 9; ++i) {
        const int L  = wv * 9216 + i * 1024 + l * 16;   // LDS byte offset
        const int r  = L / 2304;                        // row (2304 B/row)
        const int cb = L - r * 2304;
        const int c  = cb >> 2;                         // dword col 0..575
        const float* src = (c < ND_) ? (kT + r * ND_ + c)
                                     : (peT + r * NDPE_ + (c - ND_));
        gl_lds16(src, smem + (wv * 9216 + i * 1024));   // wave-uniform dest
    }
}

// rawbuf f32 [32][576] -> kbuf bf16 [32][584] + vbufT bf16 [512][34]
__device__ __forceinline__ void convert_tile(char* smem, int tid) {
    const f32x2* raw2 = (const f32x2*)smem;
    unsigned short* kb = (unsigned short*)(smem + KBUF_OFF);
    unsigned short* vt = (unsigned short*)(smem + VBUF_OFF);
    #pragma unroll
    for (int jj = 0; jj < 18; ++jj) {
        const int P  = tid + NT_ * jj;       // pair index, 288 pairs/row
        const int r  = P / 288;
        const int pc = P - r * 288;
        const f32x2 ab = raw2[P];            // rawbuf dwords 2P, 2P+1
        const unsigned w = pk_bf16(ab.x, ab.y);
        *(unsigned*)&kb[r * KROW_S + 2 * pc] = w;
        if (pc < 256) {                      // d < 512: transposed V copy
            vt[(2 * pc    ) * VT_ROW + r] = (unsigned short)(w & 0xffffu);
            vt[(2 * pc + 1) * VT_ROW + r] = (unsigned short)(w >> 16);
        }
    }
}

__global__ void qcvt(const float* __restrict__ q, const float* __restrict__ q_pe,
                     unsigned short* __restrict__ qbf) {
    const int idx = blockIdx.x * 256 + threadIdx.x;   // pair index
    if (idx >= NB_ * NH_ * (NDT_ / 2)) return;
    const int bh = idx / (NDT_ / 2), pc = idx - bh * (NDT_ / 2);
    const int c = pc * 2;
    const float* src = (c < ND_) ? (q + (size_t)bh * ND_ + c)
                                 : (q_pe + (size_t)bh * NDPE_ + (c - ND_));
    *(unsigned*)&qbf[(size_t)bh * NDT_ + c] = pk_bf16(src[0], src[1]);
}

__global__ __launch_bounds__(NT_, 2) void mla_attn(
    const float* __restrict__ k, const float* __restrict__ k_pe,
    const unsigned short* __restrict__ qbf,
    unsigned short* __restrict__ opart, float* __restrict__ mlbuf)
{
    extern __shared__ char smem[];
    const unsigned short* kbuf = (const unsigned short*)(smem + KBUF_OFF);
    const unsigned short* vbuf = (const unsigned short*)(smem + VBUF_OFF);
    unsigned short* pbuf = (unsigned short*)(smem + PBUF_OFF);

    const int chunk = blockIdx.x, b = blockIdx.y;
    const int tid = threadIdx.x;
    const int wv  = tid >> 6;
    const int l   = tid & 63;
    const int l16 = l & 15;
    const int lq  = l >> 4;

    f32x4 acc[32];
    #pragma unroll
    for (int i = 0; i < 32; ++i) acc[i] = (f32x4)0.0f;
    float m2[4]   = {-1e30f, -1e30f, -1e30f, -1e30f};
    float lsum[4] = {0.f, 0.f, 0.f, 0.f};

    // Q bf16 rows: head = l16 within this wave's 16-head group
    const unsigned short* qrowb = qbf + ((size_t)(b * NH_ + wv * 16 + l16)) * NDT_ + lq * 8;
    unsigned short* prow = pbuf + wv * 16 * PROW;

    // ---------------- prologue: DMA tile 0, convert ----------------
    {
        const int s0 = chunk * CHUNK_;
        dma_tile(smem, k + (size_t)(b * NS_ + s0) * ND_,
                       k_pe + (size_t)(b * NS_ + s0) * NDPE_, wv, l);
    }
    asm volatile("s_waitcnt vmcnt(0)" ::: "memory");
    __syncthreads();
    convert_tile(smem, tid);
    __syncthreads();

    for (int t = 0; t < NSUB_; ++t) {
        // ---------------- QK^T : scores[16h x 32s] per wave ----------------
        f32x4 sc0 = (f32x4)0.0f, sc1 = (f32x4)0.0f;
        #pragma unroll
        for (int kk = 0; kk < 18; ++kk) {
            const int d0 = kk * 32 + lq * 8;
            const s16x8 af   = *(const s16x8*)(qrowb + kk * 32);
            const s16x8 bf0  = *(const s16x8*)&kbuf[(l16     ) * KROW_S + d0];
            const s16x8 bf1v = *(const s16x8*)&kbuf[(l16 + 16) * KROW_S + d0];
            sc0 = __builtin_amdgcn_mfma_f32_16x16x32_bf16(af, bf0,  sc0, 0, 0, 0);
            sc1 = __builtin_amdgcn_mfma_f32_16x16x32_bf16(af, bf1v, sc1, 0, 0, 0);
        }
        __builtin_amdgcn_sched_barrier(0);

        // ---------------- DMA prefetch tile t+1 (zero registers held) ----------------
        if (t + 1 < NSUB_) {
            const int s0 = chunk * CHUNK_ + (t + 1) * TS_;
            dma_tile(smem, k + (size_t)(b * NS_ + s0) * ND_,
                           k_pe + (size_t)(b * NS_ + s0) * NDPE_, wv, l);
        }
        __builtin_amdgcn_sched_barrier(0);

        // ---------------- online softmax (base-2), defer-max ----------------
        float mx[4];
        #pragma unroll
        for (int r = 0; r < 4; ++r) {
            float v = fmaxf(sc0[r], sc1[r]);
            v = fmaxf(v, __shfl_xor(v, 1));
            v = fmaxf(v, __shfl_xor(v, 2));
            v = fmaxf(v, __shfl_xor(v, 4));
            v = fmaxf(v, __shfl_xor(v, 8));
            mx[r] = v * CL2;
        }
        const bool grow = (mx[0] > m2[0] + TDEF) || (mx[1] > m2[1] + TDEF) ||
                          (mx[2] > m2[2] + TDEF) || (mx[3] > m2[3] + TDEF);
        if (__any(grow)) {
            float alpha[4];
            #pragma unroll
            for (int r = 0; r < 4; ++r) {
                const float mn = fmaxf(m2[r], mx[r]);
                alpha[r] = exp2f(m2[r] - mn);
                m2[r] = mn;
                lsum[r] *= alpha[r];
            }
            #pragma unroll
            for (int nf = 0; nf < 32; ++nf) {
                acc[nf][0] *= alpha[0];
                acc[nf][1] *= alpha[1];
                acc[nf][2] *= alpha[2];
                acc[nf][3] *= alpha[3];
            }
        }
        #pragma unroll
        for (int r = 0; r < 4; ++r) {
            const float p0 = exp2f(fmaf(sc0[r], CL2, -m2[r]));
            const float p1 = exp2f(fmaf(sc1[r], CL2, -m2[r]));
            float sm = p0 + p1;
            sm += __shfl_xor(sm, 1);
            sm += __shfl_xor(sm, 2);
            sm += __shfl_xor(sm, 4);
            sm += __shfl_xor(sm, 8);
            lsum[r] += sm;
            prow[(lq * 4 + r) * PROW + l16]      = bf1(p0);
            prow[(lq * 4 + r) * PROW + 16 + l16] = bf1(p1);
        }
        // P is cross-lane consumed below (wave-local): drain LDS, pin order
        asm volatile("s_waitcnt lgkmcnt(0)" ::: "memory");
        __builtin_amdgcn_sched_barrier(0);

        // ---------------- PV : acc[16h x 512d] += P[16x32] * V[32x512] ----------------
        const s16x8 pf = *(const s16x8*)&prow[l16 * PROW + lq * 8];
        #pragma unroll
        for (int nf = 0; nf < 32; ++nf) {
            const int ro = (nf * 16 + l16) * VT_ROW + lq * 8;
            union { s16x4 h[2]; s16x8 v; } u;
            u.h[0] = *(const s16x4*)&vbuf[ro];
            u.h[1] = *(const s16x4*)&vbuf[ro + 4];
            acc[nf] = __builtin_amdgcn_mfma_f32_16x16x32_bf16(pf, u.v, acc[nf], 0, 0, 0);
        }

        // ---------------- convert DMA'd tile for next iteration ----------------
        if (t + 1 < NSUB_) {
            asm volatile("s_waitcnt vmcnt(0)" ::: "memory");
            __syncthreads();             // all PV reads done + all waves' DMA landed
            convert_tile(smem, tid);
            __syncthreads();             // kbuf/vbuf ready
        }
    }

    // ---------------- write partials (unnormalized O bf16, + m,l) ----------------
    const size_t obase = (size_t)(b * NCHUNK + chunk) * NH_ * ND_;
    #pragma unroll
    for (int nf = 0; nf < 32; ++nf) {
        #pragma unroll
        for (int r = 0; r < 4; ++r) {
            const int h = wv * 16 + lq * 4 + r;
            const int d = nf * 16 + l16;
            opart[obase + (size_t)h * ND_ + d] = bf1(acc[nf][r]);
        }
    }
    if (l16 == 0) {
        #pragma unroll
        for (int r = 0; r < 4; ++r) {
            const int h = wv * 16 + lq * 4 + r;
            const int idx = (b * NCHUNK + chunk) * NH_ + h;
            mlbuf[2 * idx]     = m2[r];
            mlbuf[2 * idx + 1] = lsum[r];
        }
    }
}

__global__ __launch_bounds__(128) void mla_combine(
    const unsigned short* __restrict__ opart, const float* __restrict__ mlbuf,
    float* __restrict__ out)
{
    const int bh = blockIdx.x;
    const int b = bh >> 7, h = bh & 127;
    const int tid = threadIdx.x;

    float mv[NCHUNK], lv[NCHUNK];
    float m = -1e30f;
    #pragma unroll
    for (int c = 0; c < NCHUNK; ++c) {
        const int idx = (b * NCHUNK + c) * NH_ + h;
        mv[c] = mlbuf[2 * idx];
        lv[c] = mlbuf[2 * idx + 1];
        m = fmaxf(m, mv[c]);
    }
    float L = 0.f, w[NCHUNK];
    #pragma unroll
    for (int c = 0; c < NCHUNK; ++c) { w[c] = exp2f(mv[c] - m); L += w[c] * lv[c]; }
    const float inv = 1.0f / L;

    const int d0 = tid * 4;
    float a0 = 0.f, a1 = 0.f, a2 = 0.f, a3 = 0.f;
    #pragma unroll
    for (int c = 0; c < NCHUNK; ++c) {
        const unsigned short* p = opart + (((size_t)(b * NCHUNK + c) * NH_ + h) * ND_ + d0);
        const unsigned u0 = *(const unsigned*)(p);
        const unsigned u1 = *(const unsigned*)(p + 2);
        a0 += w[c] * __uint_as_float((u0 & 0xffffu) << 16);
        a1 += w[c] * __uint_as_float(u0 & 0xffff0000u);
        a2 += w[c] * __uint_as_float((u1 & 0xffffu) << 16);
        a3 += w[c] * __uint_as_float(u1 & 0xffff0000u);
    }
    f32x4 res;
    res.x = a0 * inv; res.y = a1 * inv; res.z = a2 * inv; res.w = a3 * inv;
    *(f32x4*)(out + ((size_t)(b * NH_ + h) * ND_ + d0)) = res;
}

extern "C" void kernel_launch(void* const* d_in, const int* in_sizes, int n_in,
                              void* d_out, int out_size, void* d_ws, size_t ws_size,
                              hipStream_t stream) {
    const float* q    = (const float*)d_in[0];
    const float* q_pe = (const float*)d_in[1];
    const float* k    = (const float*)d_in[2];
    const float* k_pe = (const float*)d_in[3];

    unsigned short* opart = (unsigned short*)d_ws;
    float* mlbuf = (float*)((char*)d_ws + (size_t)NB_ * NCHUNK * NH_ * ND_ * sizeof(unsigned short));
    unsigned short* qbf = (unsigned short*)((char*)mlbuf + (size_t)NB_ * NCHUNK * NH_ * 2 * sizeof(float));

    const int qpairs = NB_ * NH_ * (NDT_ / 2);
    qcvt<<<(qpairs + 255) / 256, 256, 0, stream>>>(q, q_pe, qbf);
    mla_attn<<<dim3(NCHUNK, NB_), NT_, SMEM_BYTES, stream>>>(k, k_pe, qbf, opart, mlbuf);
    mla_combine<<<NB_ * NH_, 128, 0, stream>>>(opart, mlbuf, (float*)d_out);
}

// Round 5
// 123.965 us; speedup vs baseline: 2.4819x; 2.4819x over previous
//
#include <hip/hip_runtime.h>
#include <hip/hip_bf16.h>

typedef __attribute__((ext_vector_type(4))) float  f32x4;
typedef __attribute__((ext_vector_type(8))) short  s16x8;
typedef __attribute__((ext_vector_type(4))) short  s16x4;

#define NB_    16
#define NH_    128
#define NS_    4096
#define ND_    512
#define NDPE_  64
#define NCHUNK 16
#define CHUNK_ 256
#define TS_    32
#define NSUB_  8
#define NT_    1024          // 16 waves; wave pair = 16 heads (A: d 0..255, B: d 256..511)

#define KROW_S 584           // kbuf row: 576 + 8 pad shorts
#define VT_ROW 36            // vbufT row: 32 + 4 pad shorts (72 B rows, 8B-aligned b64 reads)
#define PROW   40            // pbuf row: 32 + 8 pad shorts (80 B rows, 16B-aligned b128 reads)
#define SROW   20            // sbuf row: 16 + 4 pad f32 (16B-aligned f32x4)

#define KBUF_BYTES (TS_ * KROW_S * 2)                  // 37376
#define VBUF_OFF   KBUF_BYTES
#define VBUF_BYTES (ND_ * VT_ROW * 2)                  // 36864
#define PBUF_OFF   (VBUF_OFF + VBUF_BYTES)             // 74240
#define PBUF_BYTES (16 * 16 * PROW * 2)                // 20480
#define SBUF_OFF   (PBUF_OFF + PBUF_BYTES)             // 94720
#define SBUF_BYTES (8 * 2 * TS_ * SROW * 4)            // 40960
#define SMEM_BYTES (SBUF_OFF + SBUF_BYTES)             // 135680 <= 163840

// (1/sqrt(576)) * log2(e)
#define CL2 0.06011229337037348f

__device__ __forceinline__ unsigned pk_bf16(float a, float b) {
    union { __hip_bfloat162 h2; unsigned u; } c;
    c.h2 = __float22bfloat162_rn(make_float2(a, b));
    return c.u;
}
__device__ __forceinline__ unsigned short bf1(float a) {
    union { __hip_bfloat16 h; unsigned short u; } c;
    c.h = __float2bfloat16(a);
    return c.u;
}

__global__ __launch_bounds__(NT_, 4) void mla_attn(
    const float* __restrict__ q, const float* __restrict__ q_pe,
    const float* __restrict__ k, const float* __restrict__ k_pe,
    unsigned short* __restrict__ opart, float* __restrict__ mlbuf)
{
    extern __shared__ char smem[];
    unsigned short* kbuf = (unsigned short*)(smem);              // [32][584] bf16
    unsigned short* vbuf = (unsigned short*)(smem + VBUF_OFF);   // [512][36] bf16 (V^T)
    unsigned short* pbuf = (unsigned short*)(smem + PBUF_OFF);   // 16 waves x [16][40]
    float*          sbuf = (float*)(smem + SBUF_OFF);            // 8 grp x 2 half x [32][20]

    const int chunk = blockIdx.x, b = blockIdx.y;
    const int tid   = threadIdx.x;
    const int wv    = tid >> 6;
    const int grp   = wv >> 1;       // 0..7 : 16-head group
    const int khalf = wv & 1;        // 0/1  : QK k-half  AND  PV d-half
    const int l     = tid & 63;
    const int l16   = l & 15;
    const int lq    = l >> 4;

    f32x4 acc[16];
    #pragma unroll
    for (int i = 0; i < 16; ++i) acc[i] = (f32x4)0.0f;
    float m2[4]   = {-1e30f, -1e30f, -1e30f, -1e30f};
    float lsum[4] = {0.f, 0.f, 0.f, 0.f};

    // ---------------- Q fragments: register-resident, loaded once ----------------
    s16x8 qf[9];
    {
        const int hq = b * NH_ + grp * 16 + l16;
        const float* qr  = q    + (size_t)hq * ND_;
        const float* qpr = q_pe + (size_t)hq * NDPE_;
        #pragma unroll
        for (int i = 0; i < 9; ++i) {
            const int d0 = khalf * 288 + i * 32 + lq * 8;
            f32x4 a, c;
            if (khalf == 0 || i < 7) {
                a = *(const f32x4*)(qr + d0);
                c = *(const f32x4*)(qr + d0 + 4);
            } else {
                a = *(const f32x4*)(qpr + (d0 - ND_));
                c = *(const f32x4*)(qpr + (d0 - ND_ + 4));
            }
            union { unsigned u[4]; s16x8 s; } w;
            w.u[0] = pk_bf16(a.x, a.y);
            w.u[1] = pk_bf16(a.z, a.w);
            w.u[2] = pk_bf16(c.x, c.y);
            w.u[3] = pk_bf16(c.z, c.w);
            qf[i] = w.s;
        }
    }

    unsigned short* prow = pbuf + wv * 16 * PROW;
    float* smy = sbuf + grp * (2 * TS_ * SROW) + khalf * (TS_ * SROW);
    const float* sot = sbuf + grp * (2 * TS_ * SROW) + (khalf ^ 1) * (TS_ * SROW);

    for (int t = 0; t < NSUB_; ++t) {
        // ---------------- stage tile: f32 -> bf16 kbuf + V^T scatter ----------------
        {
            const int sbase = b * NS_ + chunk * CHUNK_ + t * TS_;
            #pragma unroll
            for (int j = 0; j < 4; ++j) {           // d < 512 part: 4096 chunks
                const int c   = tid + NT_ * j;
                const int r   = c & 31;
                const int d   = (c >> 5) * 4;       // 0..508
                const f32x4 v = *(const f32x4*)(k + (size_t)(sbase + r) * ND_ + d);
                const unsigned lo = pk_bf16(v.x, v.y), hi = pk_bf16(v.z, v.w);
                *(unsigned long long*)&kbuf[r * KROW_S + d] =
                    (unsigned long long)lo | ((unsigned long long)hi << 32);
                vbuf[(d + 0) * VT_ROW + r] = (unsigned short)(lo);
                vbuf[(d + 1) * VT_ROW + r] = (unsigned short)(lo >> 16);
                vbuf[(d + 2) * VT_ROW + r] = (unsigned short)(hi);
                vbuf[(d + 3) * VT_ROW + r] = (unsigned short)(hi >> 16);
            }
            if (tid < 512) {                        // pe part: 512 chunks
                const int r  = tid & 31;
                const int dp = (tid >> 5) * 4;      // 0..60
                const f32x4 v = *(const f32x4*)(k_pe + (size_t)(sbase + r) * NDPE_ + dp);
                const unsigned lo = pk_bf16(v.x, v.y), hi = pk_bf16(v.z, v.w);
                *(unsigned long long*)&kbuf[r * KROW_S + ND_ + dp] =
                    (unsigned long long)lo | ((unsigned long long)hi << 32);
            }
        }
        __syncthreads();

        // ---------------- QK^T (own 288-dim k-half): 9 x 2 MFMA ----------------
        f32x4 sc0 = (f32x4)0.0f, sc1 = (f32x4)0.0f;
        #pragma unroll
        for (int i = 0; i < 9; ++i) {
            const int d0 = khalf * 288 + i * 32 + lq * 8;
            const s16x8 b0 = *(const s16x8*)&kbuf[(l16     ) * KROW_S + d0];
            const s16x8 b1 = *(const s16x8*)&kbuf[(l16 + 16) * KROW_S + d0];
            sc0 = __builtin_amdgcn_mfma_f32_16x16x32_bf16(qf[i], b0, sc0, 0, 0, 0);
            sc1 = __builtin_amdgcn_mfma_f32_16x16x32_bf16(qf[i], b1, sc1, 0, 0, 0);
        }

        // ---------------- exchange partial scores with partner wave ----------------
        *(f32x4*)&smy[(l16     ) * SROW + lq * 4] = sc0;
        *(f32x4*)&smy[(l16 + 16) * SROW + lq * 4] = sc1;
        __syncthreads();
        sc0 += *(const f32x4*)&sot[(l16     ) * SROW + lq * 4];
        sc1 += *(const f32x4*)&sot[(l16 + 16) * SROW + lq * 4];

        // ---------------- online softmax (base-2, scale folded) ----------------
        float alpha[4];
        #pragma unroll
        for (int r = 0; r < 4; ++r) {
            float mx = fmaxf(sc0[r], sc1[r]);
            mx = fmaxf(mx, __shfl_xor(mx, 1));
            mx = fmaxf(mx, __shfl_xor(mx, 2));
            mx = fmaxf(mx, __shfl_xor(mx, 4));
            mx = fmaxf(mx, __shfl_xor(mx, 8));
            const float mn = fmaxf(m2[r], mx * CL2);
            const float al = exp2f(m2[r] - mn);
            const float p0 = exp2f(fmaf(sc0[r], CL2, -mn));
            const float p1 = exp2f(fmaf(sc1[r], CL2, -mn));
            float sm = p0 + p1;
            sm += __shfl_xor(sm, 1);
            sm += __shfl_xor(sm, 2);
            sm += __shfl_xor(sm, 4);
            sm += __shfl_xor(sm, 8);
            lsum[r] = al * lsum[r] + sm;
            m2[r] = mn;
            alpha[r] = al;
            prow[(lq * 4 + r) * PROW + l16]      = bf1(p0);
            prow[(lq * 4 + r) * PROW + 16 + l16] = bf1(p1);
        }
        #pragma unroll
        for (int nf = 0; nf < 16; ++nf) {
            acc[nf][0] *= alpha[0];
            acc[nf][1] *= alpha[1];
            acc[nf][2] *= alpha[2];
            acc[nf][3] *= alpha[3];
        }
        // P writes are wave-locally consumed: drain LDS, pin order
        asm volatile("s_waitcnt lgkmcnt(0)" ::: "memory");
        __builtin_amdgcn_sched_barrier(0);

        // ---------------- PV (own d-half): acc[16h x 256d] += P[16x32] V[32x256] ----------------
        const s16x8 pf = *(const s16x8*)&prow[l16 * PROW + lq * 8];
        const int doff = khalf * 256;
        #pragma unroll
        for (int nf = 0; nf < 16; ++nf) {
            const int ro = (doff + nf * 16 + l16) * VT_ROW + lq * 8;
            union { s16x4 h[2]; s16x8 v; } u;
            u.h[0] = *(const s16x4*)&vbuf[ro];
            u.h[1] = *(const s16x4*)&vbuf[ro + 4];
            acc[nf] = __builtin_amdgcn_mfma_f32_16x16x32_bf16(pf, u.v, acc[nf], 0, 0, 0);
        }
        __syncthreads();   // all LDS reads done before next tile's staging writes
    }

    // ---------------- write partials (unnormalized O bf16, + m,l) ----------------
    const size_t obase = (size_t)(b * NCHUNK + chunk) * NH_ * ND_;
    const int doff = khalf * 256;
    #pragma unroll
    for (int nf = 0; nf < 16; ++nf) {
        #pragma unroll
        for (int r = 0; r < 4; ++r) {
            const int h = grp * 16 + lq * 4 + r;
            const int d = doff + nf * 16 + l16;
            opart[obase + (size_t)h * ND_ + d] = bf1(acc[nf][r]);
        }
    }
    if (khalf == 0 && l16 == 0) {
        #pragma unroll
        for (int r = 0; r < 4; ++r) {
            const int h = grp * 16 + lq * 4 + r;
            const int idx = (b * NCHUNK + chunk) * NH_ + h;
            mlbuf[2 * idx]     = m2[r];
            mlbuf[2 * idx + 1] = lsum[r];
        }
    }
}

__global__ __launch_bounds__(128) void mla_combine(
    const unsigned short* __restrict__ opart, const float* __restrict__ mlbuf,
    float* __restrict__ out)
{
    const int bh = blockIdx.x;
    const int b = bh >> 7, h = bh & 127;
    const int tid = threadIdx.x;

    float mv[NCHUNK], lv[NCHUNK];
    float m = -1e30f;
    #pragma unroll
    for (int c = 0; c < NCHUNK; ++c) {
        const int idx = (b * NCHUNK + c) * NH_ + h;
        mv[c] = mlbuf[2 * idx];
        lv[c] = mlbuf[2 * idx + 1];
        m = fmaxf(m, mv[c]);
    }
    float L = 0.f, w[NCHUNK];
    #pragma unroll
    for (int c = 0; c < NCHUNK; ++c) { w[c] = exp2f(mv[c] - m); L += w[c] * lv[c]; }
    const float inv = 1.0f / L;

    const int d0 = tid * 4;
    float a0 = 0.f, a1 = 0.f, a2 = 0.f, a3 = 0.f;
    #pragma unroll
    for (int c = 0; c < NCHUNK; ++c) {
        const unsigned short* p = opart + (((size_t)(b * NCHUNK + c) * NH_ + h) * ND_ + d0);
        const unsigned u0 = *(const unsigned*)(p);
        const unsigned u1 = *(const unsigned*)(p + 2);
        a0 += w[c] * __uint_as_float((u0 & 0xffffu) << 16);
        a1 += w[c] * __uint_as_float(u0 & 0xffff0000u);
        a2 += w[c] * __uint_as_float((u1 & 0xffffu) << 16);
        a3 += w[c] * __uint_as_float(u1 & 0xffff0000u);
    }
    f32x4 res;
    res.x = a0 * inv; res.y = a1 * inv; res.z = a2 * inv; res.w = a3 * inv;
    *(f32x4*)(out + ((size_t)(b * NH_ + h) * ND_ + d0)) = res;
}

extern "C" void kernel_launch(void* const* d_in, const int* in_sizes, int n_in,
                              void* d_out, int out_size, void* d_ws, size_t ws_size,
                              hipStream_t stream) {
    const float* q    = (const float*)d_in[0];
    const float* q_pe = (const float*)d_in[1];
    const float* k    = (const float*)d_in[2];
    const float* k_pe = (const float*)d_in[3];

    unsigned short* opart = (unsigned short*)d_ws;
    float* mlbuf = (float*)((char*)d_ws + (size_t)NB_ * NCHUNK * NH_ * ND_ * sizeof(unsigned short));

    mla_attn<<<dim3(NCHUNK, NB_), NT_, SMEM_BYTES, stream>>>(q, q_pe, k, k_pe, opart, mlbuf);
    mla_combine<<<NB_ * NH_, 128, 0, stream>>>(opart, mlbuf, (float*)d_out);
}